// Round 3
// baseline (2760.110 us; speedup 1.0000x reference)
//
#include <hip/hip_runtime.h>
#include <hip/hip_bf16.h>
#include <cstdint>

// Problem constants (match reference)
#define BB 32
#define SS 512
#define DD 768
#define VV 8192
#define KK 8
#define TT (BB * SS)        // 16384 tokens
#define NOISE_SCALE 0.1f

// argmin GEMM tiling
#define MT 128
#define NT 128
#define KT 32
#define LPAD 4              // LDS row = 128+4 = 132 floats = 528 B (16B-aligned)
#define NSPLIT 8            // each wg covers VV/NSPLIT = 1024 codes

// ---------------------------------------------------------------------------
// Kernel A: cb_sq[v] = sum_d codebook[v][d]^2   (one wave per row)
// ---------------------------------------------------------------------------
__global__ void cbsq_kernel(const float* __restrict__ cb, float* __restrict__ cbsq) {
    int row  = blockIdx.x * 4 + (threadIdx.x >> 6);
    int lane = threadIdx.x & 63;
    const float4* p = reinterpret_cast<const float4*>(cb + (size_t)row * DD);
    float s = 0.f;
#pragma unroll
    for (int w = 0; w < 3; ++w) {
        float4 v = p[lane + 64 * w];
        s += v.x * v.x + v.y * v.y + v.z * v.z + v.w * v.w;
    }
#pragma unroll
    for (int off = 32; off; off >>= 1) s += __shfl_xor(s, off, 64);
    if (lane == 0) cbsq[row] = s;
}

// ---------------------------------------------------------------------------
// Kernel B: fused fp32 GEMM + running argmin.
// scores[t][v] = cbsq[v] - 2 * <x_t, c_v>
// wg = (128-token tile) x (V/NSPLIT codes); LDS tiles stored TRANSPOSED
// ([k][m], [k][n]) so fragments load as float4 (ds_read_b128).
// grid = 128 m-tiles x 8 splits = 1024 = 4 blocks/CU exactly.
// ---------------------------------------------------------------------------
__global__ __launch_bounds__(256, 4) void argmin_kernel(
    const float* __restrict__ X,     // [TT, DD]
    const float* __restrict__ CB,    // [VV, DD]
    const float* __restrict__ cbsq,  // [VV]
    float* __restrict__ pmin,        // [NSPLIT, TT]
    int*   __restrict__ pidx)        // [NSPLIT, TT]
{
    __shared__ __align__(16) float As[KT][MT + LPAD];   // [k][m]
    __shared__ __align__(16) float Bs[KT][NT + LPAD];   // [k][n]

    const int tid = threadIdx.x;
    const int tx  = tid & 15;
    const int ty  = tid >> 4;
    const int mtile  = blockIdx.x >> 3;       // 0..127
    const int nsplit = blockIdx.x & 7;        // 0..7
    const int m0 = mtile * MT;
    const int nbase = nsplit * (VV / NSPLIT);

    float minv[8];
    int   mini[8];
#pragma unroll
    for (int j = 0; j < 8; ++j) { minv[j] = 3.4028235e38f; mini[j] = 0x7fffffff; }

    for (int nt = 0; nt < (VV / NSPLIT) / NT; ++nt) {
        const int n1 = nbase + nt * NT;

        float acc[8][8];
#pragma unroll
        for (int jm = 0; jm < 8; ++jm)
#pragma unroll
            for (int jn = 0; jn < 8; ++jn) acc[jm][jn] = 0.f;

        for (int kc = 0; kc < DD; kc += KT) {
            // stage A (128 x 32) and B (128 x 32) transposed into LDS [k][m]
            const float* Ag = X  + (size_t)m0 * DD + kc;
            const float* Bg = CB + (size_t)n1 * DD + kc;
#pragma unroll
            for (int it = 0; it < 4; ++it) {
                int L  = it * 256 + tid;
                int m  = L >> 3;            // 0..127  (8 lanes per row: coalesced 128B)
                int kq = (L & 7) << 2;      // 0,4,...,28
                float4 va = *reinterpret_cast<const float4*>(Ag + (size_t)m * DD + kq);
                As[kq + 0][m] = va.x; As[kq + 1][m] = va.y;
                As[kq + 2][m] = va.z; As[kq + 3][m] = va.w;
                float4 vb = *reinterpret_cast<const float4*>(Bg + (size_t)m * DD + kq);
                Bs[kq + 0][m] = vb.x; Bs[kq + 1][m] = vb.y;
                Bs[kq + 2][m] = vb.z; Bs[kq + 3][m] = vb.w;
            }
            __syncthreads();

#pragma unroll 4
            for (int k = 0; k < KT; ++k) {
                // 4 x ds_read_b128 per k-step: fragments contiguous over m/n
                float4 a0 = *reinterpret_cast<const float4*>(&As[k][ty * 4]);
                float4 a1 = *reinterpret_cast<const float4*>(&As[k][64 + ty * 4]);
                float4 b0 = *reinterpret_cast<const float4*>(&Bs[k][tx * 4]);
                float4 b1 = *reinterpret_cast<const float4*>(&Bs[k][64 + tx * 4]);
                float a[8] = {a0.x, a0.y, a0.z, a0.w, a1.x, a1.y, a1.z, a1.w};
                float b[8] = {b0.x, b0.y, b0.z, b0.w, b1.x, b1.y, b1.z, b1.w};
#pragma unroll
                for (int jm = 0; jm < 8; ++jm)
#pragma unroll
                    for (int jn = 0; jn < 8; ++jn)
                        acc[jm][jn] = fmaf(a[jm], b[jn], acc[jm][jn]);
            }
            __syncthreads();
        }

        // epilogue: score = cbsq[n] - 2*dot; running min, first-index tie-break
#pragma unroll
        for (int jn = 0; jn < 8; ++jn) {
            int nn = (tx << 2) + (jn & 3) + ((jn >> 2) << 6);
            int n  = n1 + nn;
            float base = cbsq[n];
#pragma unroll
            for (int jm = 0; jm < 8; ++jm) {
                float sc = fmaf(-2.f, acc[jm][jn], base);
                if (sc < minv[jm] || (sc == minv[jm] && n < mini[jm])) {
                    minv[jm] = sc; mini[jm] = n;
                }
            }
        }
    }

    // reduce across the 16 tx lanes sharing the same token set (same ty)
#pragma unroll
    for (int off = 1; off < 16; off <<= 1) {
#pragma unroll
        for (int j = 0; j < 8; ++j) {
            float ov = __shfl_xor(minv[j], off, 64);
            int   oi = __shfl_xor(mini[j], off, 64);
            if (ov < minv[j] || (ov == minv[j] && oi < mini[j])) {
                minv[j] = ov; mini[j] = oi;
            }
        }
    }
    if (tx == 0) {
#pragma unroll
        for (int j = 0; j < 8; ++j) {
            int token = m0 + (ty << 2) + (j & 3) + ((j >> 2) << 6);
            pmin[(size_t)nsplit * TT + token] = minv[j];
            pidx[(size_t)nsplit * TT + token] = mini[j];
        }
    }
}

// ---------------------------------------------------------------------------
// Kernel C: merge NSPLIT partial argmins per token
// ---------------------------------------------------------------------------
__global__ void reduce_kernel(const float* __restrict__ pmin,
                              const int* __restrict__ pidx,
                              int* __restrict__ idx) {
    int t = blockIdx.x * 256 + threadIdx.x;
    float bv = pmin[t];
    int   bi = pidx[t];
#pragma unroll
    for (int s = 1; s < NSPLIT; ++s) {
        float v = pmin[(size_t)s * TT + t];
        int   i = pidx[(size_t)s * TT + t];
        if (v < bv || (v == bv && i < bi)) { bv = v; bi = i; }
    }
    idx[t] = bi;
}

// ---------------------------------------------------------------------------
// Kernel D: mixed[t] = mean_j codebook[idx[rand_idx[t][j]*S + s]] + 0.1*noise[t]
// one wave per token
// ---------------------------------------------------------------------------
__global__ __launch_bounds__(256) void mix_kernel(
    const float* __restrict__ CB,
    const float* __restrict__ noise,
    const int*   __restrict__ ridx,   // [TT, KK]
    const int*   __restrict__ idx,    // [TT]
    float* __restrict__ out)          // [TT, DD]
{
    int wave = threadIdx.x >> 6;
    int lane = threadIdx.x & 63;
    int t = blockIdx.x * 4 + wave;
    int s = t & (SS - 1);

    const int* r = ridx + (size_t)t * KK;
    const float4* nz = reinterpret_cast<const float4*>(noise + (size_t)t * DD);
    float4* o = reinterpret_cast<float4*>(out + (size_t)t * DD);

    const float4* rows[KK];
#pragma unroll
    for (int j = 0; j < KK; ++j) {
        int g = idx[r[j] * SS + s];
        rows[j] = reinterpret_cast<const float4*>(CB + (size_t)g * DD);
    }

#pragma unroll
    for (int w = 0; w < 3; ++w) {
        int p = lane + 64 * w;
        float4 a = {0.f, 0.f, 0.f, 0.f};
#pragma unroll
        for (int j = 0; j < KK; ++j) {
            float4 c = rows[j][p];
            a.x += c.x; a.y += c.y; a.z += c.z; a.w += c.w;
        }
        float4 nv = nz[p];
        float4 res;
        res.x = a.x * 0.125f + NOISE_SCALE * nv.x;
        res.y = a.y * 0.125f + NOISE_SCALE * nv.y;
        res.z = a.z * 0.125f + NOISE_SCALE * nv.z;
        res.w = a.w * 0.125f + NOISE_SCALE * nv.w;
        o[p] = res;
    }
}

// ---------------------------------------------------------------------------
extern "C" void kernel_launch(void* const* d_in, const int* in_sizes, int n_in,
                              void* d_out, int out_size, void* d_ws, size_t ws_size,
                              hipStream_t stream) {
    const float* base  = (const float*)d_in[0];   // [B,S,D]
    const float* cb    = (const float*)d_in[1];   // [V,D]
    const float* noise = (const float*)d_in[2];   // [B,S,D]
    const int*   ridx  = (const int*)d_in[3];     // [B,S,K]
    float* out = (float*)d_out;

    // workspace layout
    float* cbsq = (float*)d_ws;                   // V floats
    float* pmin = cbsq + VV;                      // NSPLIT*TT floats
    int*   pidx = (int*)(pmin + (size_t)NSPLIT * TT);
    int*   idx  = pidx + (size_t)NSPLIT * TT;

    cbsq_kernel<<<VV / 4, 256, 0, stream>>>(cb, cbsq);
    argmin_kernel<<<(TT / MT) * NSPLIT, 256, 0, stream>>>(base, cb, cbsq, pmin, pidx);
    reduce_kernel<<<TT / 256, 256, 0, stream>>>(pmin, pidx, idx);
    mix_kernel<<<TT / 4, 256, 0, stream>>>(cb, noise, ridx, idx, out);
}

// Round 8
// 1657.732 us; speedup vs baseline: 1.6650x; 1.6650x over previous
//
#include <hip/hip_runtime.h>
#include <hip/hip_bf16.h>
#include <cstdint>

// Problem constants (match reference)
#define BB 32
#define SS 512
#define DD 768
#define VV 8192
#define KK 8
#define TT (BB * SS)        // 16384 tokens
#define NOISE_SCALE 0.1f

// MFMA argmin tiling
#define BM 128
#define BN 128
#define BK 32
#define NS 8                // code splits; ns == blockIdx%8 == XCD for L2 locality
#define NTL ((VV / NS) / BN)   // 8 n-tiles per block
#define NKC (DD / BK)          // 24 k-chunks
#define DELTA 0.25f            // rescue margin (approx score err ~5e-3; 50x headroom)

using short8  = __attribute__((ext_vector_type(8))) short;          // 8 bf16 = 4 VGPRs
using ushort8 = __attribute__((ext_vector_type(8))) unsigned short; // 16B
using f32x4   = __attribute__((ext_vector_type(4))) float;

// ---------------------------------------------------------------------------
// Kernel A: cb_sq[v] = sum_d codebook[v][d]^2   (one wave per row)
// ---------------------------------------------------------------------------
__global__ void cbsq_kernel(const float* __restrict__ cb, float* __restrict__ cbsq) {
    int row  = blockIdx.x * 4 + (threadIdx.x >> 6);
    int lane = threadIdx.x & 63;
    const float4* p = reinterpret_cast<const float4*>(cb + (size_t)row * DD);
    float s = 0.f;
#pragma unroll
    for (int w = 0; w < 3; ++w) {
        float4 v = p[lane + 64 * w];
        s += v.x * v.x + v.y * v.y + v.z * v.z + v.w * v.w;
    }
#pragma unroll
    for (int off = 32; off; off >>= 1) s += __shfl_xor(s, off, 64);
    if (lane == 0) cbsq[row] = s;
}

// ---------------------------------------------------------------------------
// top-2 insert with first-index tie-break (keeps (s1,i1) lex-min)
// ---------------------------------------------------------------------------
__device__ __forceinline__ void top2_ins(float s, int n, float& s1, int& i1,
                                         float& s2, int& i2) {
    if (s < s1 || (s == s1 && n < i1)) { s2 = s1; i2 = i1; s1 = s; i1 = n; }
    else if (s < s2 || (s == s2 && n < i2)) { s2 = s; i2 = n; }
}

// fp32 -> (hi, lo) bf16 pair by bit-truncation; x = hi + lo + O(2^-14 |x|)
__device__ __forceinline__ void bfsplit(float v, unsigned short& h, unsigned short& l) {
    uint u = __float_as_uint(v);
    h = (unsigned short)(u >> 16);
    float r = v - __uint_as_float(u & 0xffff0000u);   // exact residual
    l = (unsigned short)(__float_as_uint(r) >> 16);
}

// LDS bank swizzle: permute 16B slots (4 per 64B row) as fn of row.
// Bijective per row; write & read use the same map -> data-identical.
__device__ __forceinline__ int swz(int row, int slot) {
    return slot ^ ((row ^ (row >> 2)) & 3);
}

// ---------------------------------------------------------------------------
// Kernel P: elementwise fp32 -> (hi, lo) bf16 planes (grid covers n4 float4s)
// ---------------------------------------------------------------------------
__global__ __launch_bounds__(256) void conv_kernel(
    const float* __restrict__ src, unsigned short* __restrict__ hi,
    unsigned short* __restrict__ lo) {
    int i = blockIdx.x * 256 + threadIdx.x;   // float4 index (grid sized exactly)
    float4 v = reinterpret_cast<const float4*>(src)[i];
    ushort4 h, l;
    bfsplit(v.x, h.x, l.x); bfsplit(v.y, h.y, l.y);
    bfsplit(v.z, h.z, l.z); bfsplit(v.w, h.w, l.w);
    reinterpret_cast<ushort4*>(hi)[i] = h;
    reinterpret_cast<ushort4*>(lo)[i] = l;
}

// ---------------------------------------------------------------------------
// Kernel B: split-precision bf16 MFMA distance GEMM + fused per-token top-2.
// score[t][v] = cbsq[v] - 2*dot(x_t, c_v);  dot ~= xh*ch + xh*cl + xl*ch.
// grid = (TT/BM) x NS; block 256 (4 waves, 2x2); per-wave 64x64 sub-tile.
// PRECONV: stage pre-split bf16 planes (pure copies); else convert in-kernel.
// ---------------------------------------------------------------------------
template <bool PRECONV>
__global__ __launch_bounds__(256, 2) void argmin_mfma(
    const float* __restrict__ X,      // [TT, DD] fp32 (fallback path)
    const float* __restrict__ CB,     // [VV, DD] fp32 (fallback path)
    const unsigned short* __restrict__ Xh, const unsigned short* __restrict__ Xl,
    const unsigned short* __restrict__ CBh, const unsigned short* __restrict__ CBl,
    const float* __restrict__ cbsq,   // [VV]
    float4* __restrict__ part)        // [2*NS, TT] (s1, s2, i1, i2)
{
    // flat tiles, row stride BK=32 ushorts (64B); 16B slots swizzled via swz()
    __shared__ unsigned short Ah[BM * BK], Al[BM * BK], Bh[BM * BK], Bl[BM * BK];

    const int tid  = threadIdx.x;
    const int lane = tid & 63;
    const int wid  = tid >> 6;
    const int wm = wid >> 1, wn = wid & 1;     // 2x2 wave grid
    const int l15 = lane & 15, lg = lane >> 4;
    const int mtile = blockIdx.x >> 3;
    const int ns    = blockIdx.x & 7;
    const int m0 = mtile * BM;

    float s1[16], s2[16]; int i1[16], i2[16];
#pragma unroll
    for (int j = 0; j < 16; ++j) {
        s1[j] = INFINITY; s2[j] = INFINITY; i1[j] = 0x7fffffff; i2[j] = 0x7fffffff;
    }

    for (int nt = 0; nt < NTL; ++nt) {
        const int n1 = ns * (VV / NS) + nt * BN;

        f32x4 acc[4][4];
#pragma unroll
        for (int mt = 0; mt < 4; ++mt)
#pragma unroll
            for (int nf = 0; nf < 4; ++nf) acc[mt][nf] = (f32x4){0.f, 0.f, 0.f, 0.f};

        for (int kc = 0; kc < NKC; ++kc) {
            if constexpr (PRECONV) {
                // pure vector-copy staging from pre-split planes
                const unsigned short* Agh = Xh  + (size_t)m0 * DD + kc * BK;
                const unsigned short* Agl = Xl  + (size_t)m0 * DD + kc * BK;
                const unsigned short* Bgh = CBh + (size_t)n1 * DD + kc * BK;
                const unsigned short* Bgl = CBl + (size_t)n1 * DD + kc * BK;
#pragma unroll
                for (int i = 0; i < 2; ++i) {
                    int e = tid + 256 * i;        // 0..511
                    int row = e >> 2, q = e & 3;  // 128 rows x 4 slots (16B)
                    int so = row * BK + (swz(row, q) << 3);
                    size_t go = (size_t)row * DD + q * 8;
                    *reinterpret_cast<ushort8*>(&Ah[so]) = *reinterpret_cast<const ushort8*>(Agh + go);
                    *reinterpret_cast<ushort8*>(&Al[so]) = *reinterpret_cast<const ushort8*>(Agl + go);
                    *reinterpret_cast<ushort8*>(&Bh[so]) = *reinterpret_cast<const ushort8*>(Bgh + go);
                    *reinterpret_cast<ushort8*>(&Bl[so]) = *reinterpret_cast<const ushort8*>(Bgl + go);
                }
            } else {
                // fallback: stage + convert fp32 -> bf16 hi/lo in-kernel
                const float* Ag = X  + (size_t)m0 * DD + kc * BK;
                const float* Bg = CB + (size_t)n1 * DD + kc * BK;
#pragma unroll
                for (int i = 0; i < 4; ++i) {
                    int e = tid + 256 * i;
                    int row = e >> 3, kq = (e & 7) << 2;
                    int so = row * BK + (swz(row, kq >> 3) << 3) + (kq & 7);
                    float4 va = *reinterpret_cast<const float4*>(Ag + (size_t)row * DD + kq);
                    ushort4 ha, la;
                    bfsplit(va.x, ha.x, la.x); bfsplit(va.y, ha.y, la.y);
                    bfsplit(va.z, ha.z, la.z); bfsplit(va.w, ha.w, la.w);
                    *reinterpret_cast<ushort4*>(&Ah[so]) = ha;
                    *reinterpret_cast<ushort4*>(&Al[so]) = la;
                    float4 vb = *reinterpret_cast<const float4*>(Bg + (size_t)row * DD + kq);
                    ushort4 hb, lb;
                    bfsplit(vb.x, hb.x, lb.x); bfsplit(vb.y, hb.y, lb.y);
                    bfsplit(vb.z, hb.z, lb.z); bfsplit(vb.w, hb.w, lb.w);
                    *reinterpret_cast<ushort4*>(&Bh[so]) = hb;
                    *reinterpret_cast<ushort4*>(&Bl[so]) = lb;
                }
            }
            __syncthreads();

            // A fragments: m = l&15 within 16-row tile, k-chunk = lane>>4
            short8 ah[4], al[4];
#pragma unroll
            for (int mt = 0; mt < 4; ++mt) {
                int row = wm * 64 + mt * 16 + l15;
                int fo  = row * BK + (swz(row, lg) << 3);   // one full 16B slot
                ah[mt] = *reinterpret_cast<const short8*>(&Ah[fo]);
                al[mt] = *reinterpret_cast<const short8*>(&Al[fo]);
            }
#pragma unroll
            for (int nf = 0; nf < 4; ++nf) {
                int row = wn * 64 + nf * 16 + l15;
                int fo  = row * BK + (swz(row, lg) << 3);
                short8 bh = *reinterpret_cast<const short8*>(&Bh[fo]);
                short8 bl = *reinterpret_cast<const short8*>(&Bl[fo]);
#pragma unroll
                for (int mt = 0; mt < 4; ++mt) {
                    acc[mt][nf] = __builtin_amdgcn_mfma_f32_16x16x32_bf16(ah[mt], bh, acc[mt][nf], 0, 0, 0);
                    acc[mt][nf] = __builtin_amdgcn_mfma_f32_16x16x32_bf16(ah[mt], bl, acc[mt][nf], 0, 0, 0);
                    acc[mt][nf] = __builtin_amdgcn_mfma_f32_16x16x32_bf16(al[mt], bh, acc[mt][nf], 0, 0, 0);
                }
            }
            __syncthreads();
        }

        // fold this n-tile's scores into running top-2
        float cq[4]; int nn[4];
#pragma unroll
        for (int nf = 0; nf < 4; ++nf) {
            nn[nf] = n1 + wn * 64 + nf * 16 + l15;
            cq[nf] = cbsq[nn[nf]];
        }
#pragma unroll
        for (int mt = 0; mt < 4; ++mt)
#pragma unroll
            for (int r = 0; r < 4; ++r) {
                const int j = mt * 4 + r;
#pragma unroll
                for (int nf = 0; nf < 4; ++nf) {
                    float s = fmaf(-2.f, acc[mt][nf][r], cq[nf]);
                    top2_ins(s, nn[nf], s1[j], i1[j], s2[j], i2[j]);
                }
            }
    }

    // merge top-2 across the 16 lanes (cols) sharing each row: xor 1,2,4,8
#pragma unroll
    for (int st = 1; st < 16; st <<= 1) {
#pragma unroll
        for (int j = 0; j < 16; ++j) {
            float os1 = __shfl_xor(s1[j], st, 64); int oi1 = __shfl_xor(i1[j], st, 64);
            float os2 = __shfl_xor(s2[j], st, 64); int oi2 = __shfl_xor(i2[j], st, 64);
            top2_ins(os1, oi1, s1[j], i1[j], s2[j], i2[j]);
            top2_ins(os2, oi2, s1[j], i1[j], s2[j], i2[j]);
        }
    }
    if (l15 == 0) {
#pragma unroll
        for (int j = 0; j < 16; ++j) {
            int mt = j >> 2, r = j & 3;
            int token = m0 + wm * 64 + mt * 16 + lg * 4 + r;   // C row = (lane>>4)*4 + reg
            part[(size_t)(ns * 2 + wn) * TT + token] =
                make_float4(s1[j], s2[j], __int_as_float(i1[j]), __int_as_float(i2[j]));
        }
    }
}

// ---------------------------------------------------------------------------
// Kernel C: merge 16 partial top-2s per token; if margin small, exact fp32
// re-check of the two candidates. One wave per token.
// ---------------------------------------------------------------------------
__global__ __launch_bounds__(256) void rescue_kernel(
    const float* __restrict__ X, const float* __restrict__ CB,
    const float* __restrict__ cbsq, const float4* __restrict__ part,
    int* __restrict__ idx)
{
    int wv = threadIdx.x >> 6, lane = threadIdx.x & 63;
    int t = blockIdx.x * 4 + wv;

    float s1 = INFINITY, s2 = INFINITY; int j1 = 0x7fffffff, j2 = 0x7fffffff;
    if (lane < 16) {
        float4 p = part[(size_t)lane * TT + t];
        s1 = p.x; s2 = p.y; j1 = __float_as_int(p.z); j2 = __float_as_int(p.w);
    }
#pragma unroll
    for (int st = 1; st < 16; st <<= 1) {
        float os1 = __shfl_xor(s1, st, 64); int oi1 = __shfl_xor(j1, st, 64);
        float os2 = __shfl_xor(s2, st, 64); int oi2 = __shfl_xor(j2, st, 64);
        top2_ins(os1, oi1, s1, j1, s2, j2);
        top2_ins(os2, oi2, s1, j1, s2, j2);
    }
    s1 = __shfl(s1, 0, 64); s2 = __shfl(s2, 0, 64);
    j1 = __shfl(j1, 0, 64); j2 = __shfl(j2, 0, 64);

    int res;
    if (s2 - s1 > DELTA) {
        res = j1;                       // approx margin >> approx error: safe
    } else {
        // exact fp32 scores for both candidates
        const float* x  = X  + (size_t)t * DD;
        const float* c1 = CB + (size_t)j1 * DD;
        const float* c2 = CB + (size_t)j2 * DD;
        float p1 = 0.f, p2 = 0.f;
#pragma unroll
        for (int q = 0; q < 12; ++q) {
            int d = lane + 64 * q;
            p1 = fmaf(x[d], c1[d], p1);
            p2 = fmaf(x[d], c2[d], p2);
        }
#pragma unroll
        for (int off = 32; off; off >>= 1) {
            p1 += __shfl_xor(p1, off, 64);
            p2 += __shfl_xor(p2, off, 64);
        }
        float e1 = fmaf(-2.f, p1, cbsq[j1]);
        float e2 = fmaf(-2.f, p2, cbsq[j2]);
        res = (e1 < e2 || (e1 == e2 && j1 < j2)) ? j1 : j2;
    }
    if (lane == 0) idx[t] = res;
}

// ---------------------------------------------------------------------------
// Kernel D: mixed[t] = mean_j codebook[idx[rand_idx[t][j]*S + s]] + 0.1*noise[t]
// ---------------------------------------------------------------------------
__global__ __launch_bounds__(256) void mix_kernel(
    const float* __restrict__ CB,
    const float* __restrict__ noise,
    const int*   __restrict__ ridx,   // [TT, KK]
    const int*   __restrict__ idx,    // [TT]
    float* __restrict__ out)          // [TT, DD]
{
    int wave = threadIdx.x >> 6;
    int lane = threadIdx.x & 63;
    int t = blockIdx.x * 4 + wave;
    int s = t & (SS - 1);

    const int* r = ridx + (size_t)t * KK;
    const float4* nz = reinterpret_cast<const float4*>(noise + (size_t)t * DD);
    float4* o = reinterpret_cast<float4*>(out + (size_t)t * DD);

    const float4* rows[KK];
#pragma unroll
    for (int j = 0; j < KK; ++j) {
        int g = idx[r[j] * SS + s];
        rows[j] = reinterpret_cast<const float4*>(CB + (size_t)g * DD);
    }

#pragma unroll
    for (int w = 0; w < 3; ++w) {
        int p = lane + 64 * w;
        float4 a = {0.f, 0.f, 0.f, 0.f};
#pragma unroll
        for (int j = 0; j < KK; ++j) {
            float4 c = rows[j][p];
            a.x += c.x; a.y += c.y; a.z += c.z; a.w += c.w;
        }
        float4 nv = nz[p];
        float4 res;
        res.x = a.x * 0.125f + NOISE_SCALE * nv.x;
        res.y = a.y * 0.125f + NOISE_SCALE * nv.y;
        res.z = a.z * 0.125f + NOISE_SCALE * nv.z;
        res.w = a.w * 0.125f + NOISE_SCALE * nv.w;
        o[p] = res;
    }
}

// ---------------------------------------------------------------------------
extern "C" void kernel_launch(void* const* d_in, const int* in_sizes, int n_in,
                              void* d_out, int out_size, void* d_ws, size_t ws_size,
                              hipStream_t stream) {
    const float* base  = (const float*)d_in[0];   // [B,S,D]
    const float* cb    = (const float*)d_in[1];   // [V,D]
    const float* noise = (const float*)d_in[2];   // [B,S,D]
    const int*   ridx  = (const int*)d_in[3];     // [B,S,K]
    float* out = (float*)d_out;

    // workspace layout
    char* w = (char*)d_ws;
    float*  cbsq = (float*)w;                 w += (size_t)VV * 4;            // 32 KB
    float4* part = (float4*)w;                w += (size_t)2 * NS * TT * 16;  // 4 MB
    int*    idx  = (int*)w;                   w += (size_t)TT * 4;            // 64 KB
    unsigned short* Xh  = (unsigned short*)w; w += (size_t)TT * DD * 2;       // 25.2 MB
    unsigned short* Xl  = (unsigned short*)w; w += (size_t)TT * DD * 2;
    unsigned short* CBh = (unsigned short*)w; w += (size_t)VV * DD * 2;       // 12.6 MB
    unsigned short* CBl = (unsigned short*)w; w += (size_t)VV * DD * 2;
    const size_t need = (size_t)(w - (char*)d_ws);

    cbsq_kernel<<<VV / 4, 256, 0, stream>>>(cb, cbsq);

    if (ws_size >= need) {
        conv_kernel<<<(TT * DD / 4) / 256, 256, 0, stream>>>(base, Xh, Xl);
        conv_kernel<<<(VV * DD / 4) / 256, 256, 0, stream>>>(cb, CBh, CBl);
        argmin_mfma<true><<<(TT / BM) * NS, 256, 0, stream>>>(
            base, cb, Xh, Xl, CBh, CBl, cbsq, part);
    } else {
        argmin_mfma<false><<<(TT / BM) * NS, 256, 0, stream>>>(
            base, cb, nullptr, nullptr, nullptr, nullptr, cbsq, part);
    }

    rescue_kernel<<<TT / 4, 256, 0, stream>>>(base, cb, cbsq, part, idx);
    mix_kernel<<<TT / 4, 256, 0, stream>>>(cb, noise, ridx, idx, out);
}

// Round 10
// 1587.485 us; speedup vs baseline: 1.7387x; 1.0443x over previous
//
#include <hip/hip_runtime.h>
#include <hip/hip_bf16.h>
#include <cstdint>

// Problem constants (match reference)
#define BB 32
#define SS 512
#define DD 768
#define VV 8192
#define KK 8
#define TT (BB * SS)        // 16384 tokens
#define NOISE_SCALE 0.1f

// MFMA argmin tiling
#define BM 128
#define BN 128
#define BK 32
#define NS 8                   // code splits; ns == blockIdx%8 == XCD for L2 locality
#define NTL ((VV / NS) / BN)   // 8 n-tiles per block
#define NKC (DD / BK)          // 24 k-chunks
#define NSTEP (NTL * NKC)      // 192
#define PLANE_USH 4096         // 128x32 ushorts = 8 KB per plane per (tile,kc)
#define TILE_USH 8192          // hi|lo plane pair
#define DELTA 0.25f            // rescue margin (approx score err ~5e-3; 50x headroom)

using short8  = __attribute__((ext_vector_type(8))) short;          // 8 bf16 = 4 VGPRs
using ushort8 = __attribute__((ext_vector_type(8))) unsigned short; // 16B
using f32x4   = __attribute__((ext_vector_type(4))) float;

// async global->LDS, 16B per lane (gfx950); LDS dest = base + lane*16 (HW)
#define GLOAD_LDS16(l, g) __builtin_amdgcn_global_load_lds(                    \
    (__attribute__((address_space(1))) void*)(g),                              \
    (__attribute__((address_space(3))) void*)(l), 16, 0, 0)

// ---------------------------------------------------------------------------
// Kernel A: cb_sq[v] = sum_d codebook[v][d]^2   (one wave per row)
// ---------------------------------------------------------------------------
__global__ void cbsq_kernel(const float* __restrict__ cb, float* __restrict__ cbsq) {
    int row  = blockIdx.x * 4 + (threadIdx.x >> 6);
    int lane = threadIdx.x & 63;
    const float4* p = reinterpret_cast<const float4*>(cb + (size_t)row * DD);
    float s = 0.f;
#pragma unroll
    for (int w = 0; w < 3; ++w) {
        float4 v = p[lane + 64 * w];
        s += v.x * v.x + v.y * v.y + v.z * v.z + v.w * v.w;
    }
#pragma unroll
    for (int off = 32; off; off >>= 1) s += __shfl_xor(s, off, 64);
    if (lane == 0) cbsq[row] = s;
}

// ---------------------------------------------------------------------------
__device__ __forceinline__ void top2_ins(float s, int n, float& s1, int& i1,
                                         float& s2, int& i2) {
    if (s < s1 || (s == s1 && n < i1)) { s2 = s1; i2 = i1; s1 = s; i1 = n; }
    else if (s < s2 || (s == s2 && n < i2)) { s2 = s; i2 = n; }
}

// fp32 -> (hi, lo) bf16 pair by bit-truncation; x = hi + lo + O(2^-14 |x|)
__device__ __forceinline__ void bfsplit(float v, unsigned short& h, unsigned short& l) {
    uint u = __float_as_uint(v);
    h = (unsigned short)(u >> 16);
    float r = v - __uint_as_float(u & 0xffff0000u);   // exact residual
    l = (unsigned short)(__float_as_uint(r) >> 16);
}

// LDS bank swizzle: permute 16B slots (4 per 64B row) as fn of row. Bijective.
__device__ __forceinline__ int swz(int row, int slot) {
    return slot ^ ((row ^ (row >> 2)) & 3);
}

// ---------------------------------------------------------------------------
// Kernel P: fp32 -> tiled, PRE-SWIZZLED bf16 hi/lo planes.
// dst tile t = rtile*NKC + kc, 8192 ushorts: [hi 4096 | lo 4096];
// element (row,k) of tile at row*32 + swz(row,k>>3)*8 + (k&7)  == LDS layout,
// so global_load_lds with linear LDS dest reproduces the swizzled layout.
// ---------------------------------------------------------------------------
__global__ __launch_bounds__(256) void conv_tiled(const float* __restrict__ src,
                                                  unsigned short* __restrict__ dst) {
    int e = blockIdx.x * 256 + threadIdx.x;
    int tile = e >> 9, inner = e & 511;       // 512 threads per tile
    int row = inner >> 2, slot = inner & 3;   // 128 rows x 4 slots(16B)
    int rt = tile / NKC, kc = tile - rt * NKC;
    const float* sp = src + (size_t)(rt * BM + row) * DD + kc * BK + slot * 8;
    float4 v0 = *reinterpret_cast<const float4*>(sp);
    float4 v1 = *reinterpret_cast<const float4*>(sp + 4);
    float vv[8] = {v0.x, v0.y, v0.z, v0.w, v1.x, v1.y, v1.z, v1.w};
    ushort8 h, l;
#pragma unroll
    for (int i = 0; i < 8; ++i) {
        unsigned short hh, ll;
        bfsplit(vv[i], hh, ll);
        h[i] = hh; l[i] = ll;
    }
    size_t base = (size_t)tile * TILE_USH + row * BK + swz(row, slot) * 8;
    *reinterpret_cast<ushort8*>(dst + base) = h;
    *reinterpret_cast<ushort8*>(dst + base + PLANE_USH) = l;
}

// ---------------------------------------------------------------------------
// Kernel B: split-precision bf16 MFMA distance GEMM + fused per-token top-2.
// dbuf LDS + async global_load_lds staging (2-phase: issue s+1, compute s,
// one __syncthreads per step = the template's vmcnt(0)+barrier drain point).
// wave w stages plane w (0=Ah,1=Al,2=Bh,3=Bl): 8 x 1KB chunks.
// ---------------------------------------------------------------------------
__global__ __launch_bounds__(256) void argmin_async(
    const unsigned short* __restrict__ Axt,  // [128 mtiles][24 kc][hi|lo]
    const unsigned short* __restrict__ Bxt,  // [64 ntiles][24 kc][hi|lo]
    const float* __restrict__ cbsq,
    float4* __restrict__ part)               // [2*NS, TT] (s1, s2, i1, i2)
{
    __shared__ unsigned short lds[2][4][PLANE_USH];   // 64 KB

    const int tid  = threadIdx.x;
    const int lane = tid & 63;
    const int wid  = tid >> 6;
    const int wm = wid >> 1, wn = wid & 1;     // 2x2 wave grid
    const int l15 = lane & 15, lg = lane >> 4;
    const int mtile = blockIdx.x >> 3;
    const int ns    = blockIdx.x & 7;
    const int m0 = mtile * BM;

    float s1[16], s2[16]; int i1[16], i2[16];
#pragma unroll
    for (int j = 0; j < 16; ++j) {
        s1[j] = INFINITY; s2[j] = INFINITY; i1[j] = 0x7fffffff; i2[j] = 0x7fffffff;
    }

    f32x4 acc[4][4];
#pragma unroll
    for (int mt = 0; mt < 4; ++mt)
#pragma unroll
        for (int nf = 0; nf < 4; ++nf) acc[mt][nf] = (f32x4){0.f, 0.f, 0.f, 0.f};

    auto stage = [&](int b, int snt, int skc) {
        const unsigned short* src = (wid < 2)
            ? Axt + (size_t)(mtile * NKC + skc) * TILE_USH
            : Bxt + (size_t)((ns * NTL + snt) * NKC + skc) * TILE_USH;
        src += (wid & 1) * PLANE_USH + lane * 8;   // plane select + per-lane 16B
        unsigned short* dst = &lds[b][wid][0];
#pragma unroll
        for (int c = 0; c < 8; ++c)
            GLOAD_LDS16(dst + c * 512, src + c * 512);
    };

    stage(0, 0, 0);
    __syncthreads();

    int cur = 0, nt = 0, kc = 0;
    for (int s = 0; s < NSTEP; ++s) {
        int nnt = nt, nkc = kc + 1;
        if (nkc == NKC) { nkc = 0; ++nnt; }
        if (s + 1 < NSTEP) stage(cur ^ 1, nnt, nkc);   // prefetch next tile

        const unsigned short (&L)[4][PLANE_USH] = lds[cur];
        short8 ah[4], al[4];
#pragma unroll
        for (int mt = 0; mt < 4; ++mt) {
            int row = wm * 64 + mt * 16 + l15;
            int fo  = row * BK + swz(row, lg) * 8;
            ah[mt] = *reinterpret_cast<const short8*>(&L[0][fo]);
            al[mt] = *reinterpret_cast<const short8*>(&L[1][fo]);
        }
#pragma unroll
        for (int nf = 0; nf < 4; ++nf) {
            int row = wn * 64 + nf * 16 + l15;
            int fo  = row * BK + swz(row, lg) * 8;
            short8 bh = *reinterpret_cast<const short8*>(&L[2][fo]);
            short8 bl = *reinterpret_cast<const short8*>(&L[3][fo]);
#pragma unroll
            for (int mt = 0; mt < 4; ++mt) {
                acc[mt][nf] = __builtin_amdgcn_mfma_f32_16x16x32_bf16(ah[mt], bh, acc[mt][nf], 0, 0, 0);
                acc[mt][nf] = __builtin_amdgcn_mfma_f32_16x16x32_bf16(ah[mt], bl, acc[mt][nf], 0, 0, 0);
                acc[mt][nf] = __builtin_amdgcn_mfma_f32_16x16x32_bf16(al[mt], bh, acc[mt][nf], 0, 0, 0);
            }
        }

        if (kc == NKC - 1) {   // n-tile finished: fold scores into top-2, reset acc
            int n1 = ns * (VV / NS) + nt * BN;
            float cq[4]; int nn[4];
#pragma unroll
            for (int nf = 0; nf < 4; ++nf) {
                nn[nf] = n1 + wn * 64 + nf * 16 + l15;
                cq[nf] = cbsq[nn[nf]];
            }
#pragma unroll
            for (int mt = 0; mt < 4; ++mt)
#pragma unroll
                for (int r = 0; r < 4; ++r) {
                    const int j = mt * 4 + r;
#pragma unroll
                    for (int nf = 0; nf < 4; ++nf) {
                        float sc = fmaf(-2.f, acc[mt][nf][r], cq[nf]);
                        top2_ins(sc, nn[nf], s1[j], i1[j], s2[j], i2[j]);
                    }
                }
#pragma unroll
            for (int mt = 0; mt < 4; ++mt)
#pragma unroll
                for (int nf = 0; nf < 4; ++nf) acc[mt][nf] = (f32x4){0.f, 0.f, 0.f, 0.f};
        }
        __syncthreads();   // drains prefetch (vmcnt0) + guards buffer reuse
        cur ^= 1; nt = nnt; kc = nkc;
    }

    // merge top-2 across the 16 lanes (cols) sharing each row: xor 1,2,4,8
#pragma unroll
    for (int st = 1; st < 16; st <<= 1) {
#pragma unroll
        for (int j = 0; j < 16; ++j) {
            float os1 = __shfl_xor(s1[j], st, 64); int oi1 = __shfl_xor(i1[j], st, 64);
            float os2 = __shfl_xor(s2[j], st, 64); int oi2 = __shfl_xor(i2[j], st, 64);
            top2_ins(os1, oi1, s1[j], i1[j], s2[j], i2[j]);
            top2_ins(os2, oi2, s1[j], i1[j], s2[j], i2[j]);
        }
    }
    if (l15 == 0) {
#pragma unroll
        for (int j = 0; j < 16; ++j) {
            int mt = j >> 2, r = j & 3;
            int token = m0 + wm * 64 + mt * 16 + lg * 4 + r;   // C row = (lane>>4)*4 + reg
            part[(size_t)(ns * 2 + wn) * TT + token] =
                make_float4(s1[j], s2[j], __int_as_float(i1[j]), __int_as_float(i2[j]));
        }
    }
}

// ---------------------------------------------------------------------------
// Fallback (small ws): r8 convert-in-kernel variant, verified-passing logic.
// ---------------------------------------------------------------------------
__global__ __launch_bounds__(256) void argmin_fb(
    const float* __restrict__ X, const float* __restrict__ CB,
    const float* __restrict__ cbsq, float4* __restrict__ part)
{
    __shared__ unsigned short Ah[BM * BK], Al[BM * BK], Bh[BM * BK], Bl[BM * BK];
    const int tid = threadIdx.x, lane = tid & 63, wid = tid >> 6;
    const int wm = wid >> 1, wn = wid & 1;
    const int l15 = lane & 15, lg = lane >> 4;
    const int mtile = blockIdx.x >> 3, ns = blockIdx.x & 7;
    const int m0 = mtile * BM;

    float s1[16], s2[16]; int i1[16], i2[16];
#pragma unroll
    for (int j = 0; j < 16; ++j) {
        s1[j] = INFINITY; s2[j] = INFINITY; i1[j] = 0x7fffffff; i2[j] = 0x7fffffff;
    }
    for (int nt = 0; nt < NTL; ++nt) {
        const int n1 = ns * (VV / NS) + nt * BN;
        f32x4 acc[4][4];
#pragma unroll
        for (int mt = 0; mt < 4; ++mt)
#pragma unroll
            for (int nf = 0; nf < 4; ++nf) acc[mt][nf] = (f32x4){0.f, 0.f, 0.f, 0.f};
        for (int kc = 0; kc < NKC; ++kc) {
            const float* Ag = X  + (size_t)m0 * DD + kc * BK;
            const float* Bg = CB + (size_t)n1 * DD + kc * BK;
#pragma unroll
            for (int i = 0; i < 4; ++i) {
                int e = tid + 256 * i;
                int row = e >> 3, kq = (e & 7) << 2;
                int so = row * BK + (swz(row, kq >> 3) << 3) + (kq & 7);
                float4 va = *reinterpret_cast<const float4*>(Ag + (size_t)row * DD + kq);
                ushort4 ha, la;
                bfsplit(va.x, ha.x, la.x); bfsplit(va.y, ha.y, la.y);
                bfsplit(va.z, ha.z, la.z); bfsplit(va.w, ha.w, la.w);
                *reinterpret_cast<ushort4*>(&Ah[so]) = ha;
                *reinterpret_cast<ushort4*>(&Al[so]) = la;
                float4 vb = *reinterpret_cast<const float4*>(Bg + (size_t)row * DD + kq);
                ushort4 hb, lb;
                bfsplit(vb.x, hb.x, lb.x); bfsplit(vb.y, hb.y, lb.y);
                bfsplit(vb.z, hb.z, lb.z); bfsplit(vb.w, hb.w, lb.w);
                *reinterpret_cast<ushort4*>(&Bh[so]) = hb;
                *reinterpret_cast<ushort4*>(&Bl[so]) = lb;
            }
            __syncthreads();
            short8 ah[4], al[4];
#pragma unroll
            for (int mt = 0; mt < 4; ++mt) {
                int row = wm * 64 + mt * 16 + l15;
                int fo  = row * BK + (swz(row, lg) << 3);
                ah[mt] = *reinterpret_cast<const short8*>(&Ah[fo]);
                al[mt] = *reinterpret_cast<const short8*>(&Al[fo]);
            }
#pragma unroll
            for (int nf = 0; nf < 4; ++nf) {
                int row = wn * 64 + nf * 16 + l15;
                int fo  = row * BK + (swz(row, lg) << 3);
                short8 bh = *reinterpret_cast<const short8*>(&Bh[fo]);
                short8 bl = *reinterpret_cast<const short8*>(&Bl[fo]);
#pragma unroll
                for (int mt = 0; mt < 4; ++mt) {
                    acc[mt][nf] = __builtin_amdgcn_mfma_f32_16x16x32_bf16(ah[mt], bh, acc[mt][nf], 0, 0, 0);
                    acc[mt][nf] = __builtin_amdgcn_mfma_f32_16x16x32_bf16(ah[mt], bl, acc[mt][nf], 0, 0, 0);
                    acc[mt][nf] = __builtin_amdgcn_mfma_f32_16x16x32_bf16(al[mt], bh, acc[mt][nf], 0, 0, 0);
                }
            }
            __syncthreads();
        }
        float cq[4]; int nn[4];
#pragma unroll
        for (int nf = 0; nf < 4; ++nf) {
            nn[nf] = n1 + wn * 64 + nf * 16 + l15;
            cq[nf] = cbsq[nn[nf]];
        }
#pragma unroll
        for (int mt = 0; mt < 4; ++mt)
#pragma unroll
            for (int r = 0; r < 4; ++r) {
                const int j = mt * 4 + r;
#pragma unroll
                for (int nf = 0; nf < 4; ++nf) {
                    float sc = fmaf(-2.f, acc[mt][nf][r], cq[nf]);
                    top2_ins(sc, nn[nf], s1[j], i1[j], s2[j], i2[j]);
                }
            }
    }
#pragma unroll
    for (int st = 1; st < 16; st <<= 1) {
#pragma unroll
        for (int j = 0; j < 16; ++j) {
            float os1 = __shfl_xor(s1[j], st, 64); int oi1 = __shfl_xor(i1[j], st, 64);
            float os2 = __shfl_xor(s2[j], st, 64); int oi2 = __shfl_xor(i2[j], st, 64);
            top2_ins(os1, oi1, s1[j], i1[j], s2[j], i2[j]);
            top2_ins(os2, oi2, s1[j], i1[j], s2[j], i2[j]);
        }
    }
    if (l15 == 0) {
#pragma unroll
        for (int j = 0; j < 16; ++j) {
            int mt = j >> 2, r = j & 3;
            int token = m0 + wm * 64 + mt * 16 + lg * 4 + r;
            part[(size_t)(ns * 2 + wn) * TT + token] =
                make_float4(s1[j], s2[j], __int_as_float(i1[j]), __int_as_float(i2[j]));
        }
    }
}

// ---------------------------------------------------------------------------
// Kernel C: merge 16 partial top-2s; exact fp32 re-check if margin < DELTA.
// ---------------------------------------------------------------------------
__global__ __launch_bounds__(256) void rescue_kernel(
    const float* __restrict__ X, const float* __restrict__ CB,
    const float* __restrict__ cbsq, const float4* __restrict__ part,
    int* __restrict__ idx)
{
    int wv = threadIdx.x >> 6, lane = threadIdx.x & 63;
    int t = blockIdx.x * 4 + wv;

    float s1 = INFINITY, s2 = INFINITY; int j1 = 0x7fffffff, j2 = 0x7fffffff;
    if (lane < 16) {
        float4 p = part[(size_t)lane * TT + t];
        s1 = p.x; s2 = p.y; j1 = __float_as_int(p.z); j2 = __float_as_int(p.w);
    }
#pragma unroll
    for (int st = 1; st < 16; st <<= 1) {
        float os1 = __shfl_xor(s1, st, 64); int oi1 = __shfl_xor(j1, st, 64);
        float os2 = __shfl_xor(s2, st, 64); int oi2 = __shfl_xor(j2, st, 64);
        top2_ins(os1, oi1, s1, j1, s2, j2);
        top2_ins(os2, oi2, s1, j1, s2, j2);
    }
    s1 = __shfl(s1, 0, 64); s2 = __shfl(s2, 0, 64);
    j1 = __shfl(j1, 0, 64); j2 = __shfl(j2, 0, 64);

    int res;
    if (s2 - s1 > DELTA) {
        res = j1;
    } else {
        const float* x  = X  + (size_t)t * DD;
        const float* c1 = CB + (size_t)j1 * DD;
        const float* c2 = CB + (size_t)j2 * DD;
        float p1 = 0.f, p2 = 0.f;
#pragma unroll
        for (int q = 0; q < 12; ++q) {
            int d = lane + 64 * q;
            p1 = fmaf(x[d], c1[d], p1);
            p2 = fmaf(x[d], c2[d], p2);
        }
#pragma unroll
        for (int off = 32; off; off >>= 1) {
            p1 += __shfl_xor(p1, off, 64);
            p2 += __shfl_xor(p2, off, 64);
        }
        float e1 = fmaf(-2.f, p1, cbsq[j1]);
        float e2 = fmaf(-2.f, p2, cbsq[j2]);
        res = (e1 < e2 || (e1 == e2 && j1 < j2)) ? j1 : j2;
    }
    if (lane == 0) idx[t] = res;
}

// ---------------------------------------------------------------------------
// Kernel D: mixed[t] = mean_j codebook[idx[rand_idx[t][j]*S + s]] + 0.1*noise[t]
// ---------------------------------------------------------------------------
__global__ __launch_bounds__(256) void mix_kernel(
    const float* __restrict__ CB,
    const float* __restrict__ noise,
    const int*   __restrict__ ridx,   // [TT, KK]
    const int*   __restrict__ idx,    // [TT]
    float* __restrict__ out)          // [TT, DD]
{
    int wave = threadIdx.x >> 6;
    int lane = threadIdx.x & 63;
    int t = blockIdx.x * 4 + wave;
    int s = t & (SS - 1);

    const int* r = ridx + (size_t)t * KK;
    const float4* nz = reinterpret_cast<const float4*>(noise + (size_t)t * DD);
    float4* o = reinterpret_cast<float4*>(out + (size_t)t * DD);

    const float4* rows[KK];
#pragma unroll
    for (int j = 0; j < KK; ++j) {
        int g = idx[r[j] * SS + s];
        rows[j] = reinterpret_cast<const float4*>(CB + (size_t)g * DD);
    }

#pragma unroll
    for (int w = 0; w < 3; ++w) {
        int p = lane + 64 * w;
        float4 a = {0.f, 0.f, 0.f, 0.f};
#pragma unroll
        for (int j = 0; j < KK; ++j) {
            float4 c = rows[j][p];
            a.x += c.x; a.y += c.y; a.z += c.z; a.w += c.w;
        }
        float4 nv = nz[p];
        float4 res;
        res.x = a.x * 0.125f + NOISE_SCALE * nv.x;
        res.y = a.y * 0.125f + NOISE_SCALE * nv.y;
        res.z = a.z * 0.125f + NOISE_SCALE * nv.z;
        res.w = a.w * 0.125f + NOISE_SCALE * nv.w;
        o[p] = res;
    }
}

// ---------------------------------------------------------------------------
extern "C" void kernel_launch(void* const* d_in, const int* in_sizes, int n_in,
                              void* d_out, int out_size, void* d_ws, size_t ws_size,
                              hipStream_t stream) {
    const float* base  = (const float*)d_in[0];   // [B,S,D]
    const float* cb    = (const float*)d_in[1];   // [V,D]
    const float* noise = (const float*)d_in[2];   // [B,S,D]
    const int*   ridx  = (const int*)d_in[3];     // [B,S,K]
    float* out = (float*)d_out;

    // workspace layout (~80 MB)
    char* w = (char*)d_ws;
    float*  cbsq = (float*)w;                 w += (size_t)VV * 4;            // 32 KB
    float4* part = (float4*)w;                w += (size_t)2 * NS * TT * 16;  // 4 MB
    int*    idx  = (int*)w;                   w += (size_t)TT * 4;            // 64 KB
    unsigned short* Axt = (unsigned short*)w; w += (size_t)128 * NKC * TILE_USH * 2; // 50.3 MB
    unsigned short* Bxt = (unsigned short*)w; w += (size_t)64  * NKC * TILE_USH * 2; // 25.2 MB
    const size_t need = (size_t)(w - (char*)d_ws);

    cbsq_kernel<<<VV / 4, 256, 0, stream>>>(cb, cbsq);

    if (ws_size >= need) {
        conv_tiled<<<(128 * NKC * 512) / 256, 256, 0, stream>>>(base, Axt);
        conv_tiled<<<(64  * NKC * 512) / 256, 256, 0, stream>>>(cb, Bxt);
        argmin_async<<<(TT / BM) * NS, 256, 0, stream>>>(Axt, Bxt, cbsq, part);
    } else {
        argmin_fb<<<(TT / BM) * NS, 256, 0, stream>>>(base, cb, cbsq, part);
    }

    rescue_kernel<<<TT / 4, 256, 0, stream>>>(base, cb, cbsq, part, idx);
    mix_kernel<<<TT / 4, 256, 0, stream>>>(cb, noise, ridx, idx, out);
}